// Round 5
// baseline (57.642 us; speedup 1.0000x reference)
//
#include <hip/hip_runtime.h>

#define H_STEPS 200
#define DT 0.01f
#define K_SPRING 100.0f
#define NCH 6   // six 32-step chunks; last 8 steps via direct per-lane loads

__device__ __forceinline__ void step(float u, float& x1, float& v1,
                                     float& x2, float& v2) {
    float pen     = x1 + 1.0f - x2;
    float contact = fmaxf(pen, 0.0f);
    float Fc      = -K_SPRING * contact;
    float F1      = u + Fc - v1;      // C = 1
    float F2      = -Fc - v2;
    v1 += F1 * DT;
    v2 += F2 * DT;
    x1 += v1 * DT;
    x2 += v2 * DT;
}

// {coalesced, deep} quadrant: all 48 chunk loads (8 rows x 128B contiguous per
// instr) reg-staged up front for a ~50-deep per-wave pipeline; per-chunk
// wave-local LDS transpose (XOR-swizzled, conflict-free b128 both sides).
// No __syncthreads anywhere -- it would drain vmcnt(0) and kill the pipeline.
__global__ __launch_bounds__(256, 2)   // 2 waves/EU -> 256-VGPR budget
void pushing_env_kernel(const float* __restrict__ u_seq,
                        const float* __restrict__ x1_0,
                        const float* __restrict__ v1_0,
                        const float* __restrict__ x2_0,
                        const float* __restrict__ v2_0,
                        const float* __restrict__ goal,
                        float* __restrict__ out, int B) {
    __shared__ float4 lds[4][64 * 8];   // 8KB per wave, 32KB per block
    const int tid  = threadIdx.x;
    const int wave = tid >> 6;
    const int lane = tid & 63;
    const int b0w  = blockIdx.x * 256 + wave * 64;  // wave's first batch row
    const int b    = b0w + lane;

    // States first: their in-order completion precedes the staged loads, so
    // their use needs only a high-count vmcnt (no pipeline drain).
    float x1 = x1_0[b];
    float v1 = v1_0[b];
    float x2 = x2_0[b];
    float v2 = v2_0[b];
    const float g = goal[0];   // uniform -> s_load

    const int lrow = lane >> 3;   // row within 8-row group (0..7)
    const int lq   = lane & 7;    // qword slot within chunk (0..7)
    const float* ubase = u_seq + (size_t)b0w * H_STEPS;

    // Staged coalesced loads: instr (c,k) covers rows k*8..k*8+7, qwords
    // 8c..8c+7 (128B contiguous per row-segment). All issued before any use.
    float4 r[NCH][8];
    #pragma unroll
    for (int c = 0; c < NCH; ++c) {
        #pragma unroll
        for (int k = 0; k < 8; ++k) {
            const int row = k * 8 + lrow;
            r[c][k] = *reinterpret_cast<const float4*>(
                ubase + (size_t)row * H_STEPS + (8 * c + lq) * 4);
        }
    }
    // Tail (steps 192..199): own row, 2 divergent loads - issued last.
    const float4* urow = reinterpret_cast<const float4*>(
        u_seq + (size_t)b * H_STEPS);
    float4 t0 = urow[48];
    float4 t1 = urow[49];

    float4* lw = lds[wave];   // wave-private region: no cross-wave sharing

    #pragma unroll
    for (int c = 0; c < NCH; ++c) {
        // Write phase: reg k holds row R=k*8+lrow, slot lq -> swizzled qword.
        #pragma unroll
        for (int k = 0; k < 8; ++k) {
            const int R = k * 8 + lrow;
            lw[R * 8 + (lq ^ lrow)] = r[c][k];   // R&7 == lrow
        }
        __builtin_amdgcn_wave_barrier();  // sched fence; DS is in-order per wave
        // Read + compute: lane l owns row l; q-th read = qwords 8c+q.
        #pragma unroll
        for (int q = 0; q < 8; ++q) {
            float4 u4 = lw[lane * 8 + (q ^ (lane & 7))];
            step(u4.x, x1, v1, x2, v2);
            step(u4.y, x1, v1, x2, v2);
            step(u4.z, x1, v1, x2, v2);
            step(u4.w, x1, v1, x2, v2);
        }
        __builtin_amdgcn_wave_barrier();  // reads retire before next overwrite
    }

    // Tail 8 steps from direct registers.
    step(t0.x, x1, v1, x2, v2);
    step(t0.y, x1, v1, x2, v2);
    step(t0.z, x1, v1, x2, v2);
    step(t0.w, x1, v1, x2, v2);
    step(t1.x, x1, v1, x2, v2);
    step(t1.y, x1, v1, x2, v2);
    step(t1.z, x1, v1, x2, v2);
    step(t1.w, x1, v1, x2, v2);

    float d = x2 - g;
    out[b]         = d * d;   // loss
    out[B + b]     = x1;
    out[2 * B + b] = x2;
}

extern "C" void kernel_launch(void* const* d_in, const int* in_sizes, int n_in,
                              void* d_out, int out_size, void* d_ws, size_t ws_size,
                              hipStream_t stream) {
    const float* u_seq = (const float*)d_in[0];
    const float* x1_0  = (const float*)d_in[1];
    const float* v1_0  = (const float*)d_in[2];
    const float* x2_0  = (const float*)d_in[3];
    const float* v2_0  = (const float*)d_in[4];
    const float* goal  = (const float*)d_in[5];
    float* out = (float*)d_out;

    const int B = in_sizes[1];  // 131072
    const int grid = B / 256;   // 512 blocks x 256 threads
    pushing_env_kernel<<<grid, 256, 0, stream>>>(u_seq, x1_0, v1_0, x2_0,
                                                 v2_0, goal, out, B);
}